// Round 6
// baseline (388.067 us; speedup 1.0000x reference)
//
#include <hip/hip_runtime.h>
#include <math.h>

#define SA    8
#define NKEYS 100000
#define NP    100096      // padded row stride for s_i (782*128)
#define DK    64
#define DA    2048
#define BB    64
#define KMAX  32
#define NBLK  782         // k_sim blocks
#define NRP   3128        // NBLK*4 R-partials per b
#define NRPP  3136        // padded row stride for Rp2
static constexpr float EPSF = 1e-8f;

typedef short  bf16x8 __attribute__((ext_vector_type(8)));
typedef float  f32x4  __attribute__((ext_vector_type(4)));

// RNE bf16 split: x ~= hi + lo, residual <= 2^-18 |x|
__device__ inline void split2(float x, unsigned short& h, unsigned short& l) {
  unsigned u = __float_as_uint(x);
  unsigned r = u + 0x7FFFu + ((u >> 16) & 1u);
  h = (unsigned short)(r >> 16);
  float hf = __uint_as_float(r & 0xFFFF0000u);
  float lo = x - hf;                    // exact
  unsigned ul = __float_as_uint(lo);
  unsigned rl = ul + 0x7FFFu + ((ul >> 16) & 1u);
  l = (unsigned short)(rl >> 16);
}

// ---------------- kernel 1: queries[b,s,k] = sum_a W_Q[s,k,a]*z[b,a] ----------------
// one wave per (b,s,k) dot of length 2048; fully coalesced.
// NOTE: measured champion config. Register retiles (2x2, 4x4) measured NEUTRAL-to-
// WORSE (r0/r4): TLP (32768 waves) already hides cache latency; do not retile.
__global__ __launch_bounds__(256) void k_queries(const float* __restrict__ z,
                                                 const float* __restrict__ WQ,
                                                 float* __restrict__ q) {
  const int t = blockIdx.x * 4 + (threadIdx.x >> 6);   // 0..32767 = b*512 + s*64 + k
  const int lane = threadIdx.x & 63;
  const int b = t >> 9, sk = t & 511;
  const float4* w4 = (const float4*)WQ + (size_t)sk * 512;
  const float4* z4 = (const float4*)z + (size_t)b * 512;
  float acc = 0.f;
#pragma unroll
  for (int i = 0; i < 8; ++i) {
    float4 a = w4[lane + 64 * i];
    float4 c = z4[lane + 64 * i];
    acc = fmaf(a.x, c.x, fmaf(a.y, c.y, fmaf(a.z, c.z, fmaf(a.w, c.w, acc))));
  }
#pragma unroll
  for (int o = 32; o; o >>= 1) acc += __shfl_xor(acc, o);
  if (lane == 0) q[(b * SA + (sk >> 6)) * DK + (sk & 63)] = acc;
}

// ---------------- kernel 1b: normalize q rows, split to bf16 hi/lo [s][b][k]; softmax(aw) ----------------
__global__ __launch_bounds__(256) void k_norm(const float* __restrict__ q,
                                              const float* __restrict__ aw,
                                              unsigned short* __restrict__ qh,
                                              unsigned short* __restrict__ ql,
                                              float* __restrict__ wbuf) {
  const int t = blockIdx.x * 4 + (threadIdx.x >> 6);   // 0..511 = b*8+s
  const int lane = threadIdx.x & 63;
  float x = q[t * DK + lane];
  float ss = x * x;
#pragma unroll
  for (int o = 32; o; o >>= 1) ss += __shfl_xor(ss, o);
  float xn = x / (sqrtf(ss) + EPSF);
  unsigned short h, l;
  split2(xn, h, l);
  const int b = t >> 3, s = t & 7;
  const int o = (s * BB + b) * DK + lane;
  qh[o] = h; ql[o] = l;
  if (blockIdx.x == 0 && threadIdx.x == 0) {
    float m = -INFINITY;
    for (int s2 = 0; s2 < SA; ++s2) m = fmaxf(m, aw[s2]);
    float e[SA], sum = 0.f;
    for (int s2 = 0; s2 < SA; ++s2) { e[s2] = __expf(aw[s2] - m); sum += e[s2]; }
    for (int s2 = 0; s2 < SA; ++s2) wbuf[s2] = e[s2] / sum;
  }
}

// ---------------- kernel 2: s_i via 4-pass split-bf16 MFMA + fused R-partials ----------------
// 782 blocks x 256 thr (4 waves). Block tile 64b x 128n; wave = 64b x 32n.
// LDS 48 KB -> 3 blocks/CU. Register-prefetch next s-tile during MFMA.
// Epilogue computes per-(block,wave) partials of R[b] = sum_n g*exp(s_i) while
// the s_i values are still in registers (removes the transcendental storm from
// k_topk_a, which ran at only 2 waves/SIMD).
__global__ __launch_bounds__(256, 3) void k_sim(const float* __restrict__ pk,
                                                const unsigned short* __restrict__ qh,
                                                const unsigned short* __restrict__ ql,
                                                const float* __restrict__ wbuf,
                                                const float* __restrict__ lam_p,
                                                const float* __restrict__ tau_p,
                                                float* __restrict__ si,
                                                float* __restrict__ Rp2) {
  __shared__ unsigned short Ah[64 * 64], Al[64 * 64];     // 8 KB each
  __shared__ unsigned short Bh[128 * 64], Bl[128 * 64];   // 16 KB each
  const int tid = threadIdx.x;
  const int wave = tid >> 6, lane = tid & 63;
  const int n0 = blockIdx.x * 128;
  const int c16 = tid & 15;          // float4 column within row
  const int rg  = tid >> 4;          // 0..15 row group
  const int lm = lane & 15, lq = lane >> 4;
  const int wn0 = wave * 32;

  f32x4 acc[4][2];
#pragma unroll
  for (int mi = 0; mi < 4; ++mi)
#pragma unroll
    for (int ni = 0; ni < 2; ++ni) acc[mi][ni] = (f32x4){0.f, 0.f, 0.f, 0.f};

  float4 breg[8];
  auto issueB = [&](int s) {
#pragma unroll
    for (int p = 0; p < 8; ++p) {
      int n = n0 + rg + 16 * p; if (n >= NKEYS) n = NKEYS - 1;
      breg[p] = *(const float4*)(pk + ((size_t)s * NKEYS + n) * DK + c16 * 4);
    }
  };
  issueB(0);

  for (int s = 0; s < SA; ++s) {
    // A staging regs (qh/ql are tiny & L2-hot)
    ushort4 arh[4], arl[4];
#pragma unroll
    for (int p = 0; p < 4; ++p) {
      int r = rg + 16 * p;
      int o = (s * BB + r) * DK + c16 * 4;
      arh[p] = *(const ushort4*)(qh + o);
      arl[p] = *(const ushort4*)(ql + o);
    }
    const float wsc = wbuf[s];
    // per-row ||k||^2: partial dot + reduce over the 16 lanes sharing the row
    float ssr[8];
#pragma unroll
    for (int p = 0; p < 8; ++p) {
      float4 v = breg[p];
      float d = v.x * v.x + v.y * v.y + v.z * v.z + v.w * v.w;
      d += __shfl_xor(d, 1); d += __shfl_xor(d, 2);
      d += __shfl_xor(d, 4); d += __shfl_xor(d, 8);
      ssr[p] = d;
    }
    // scale, split, write B tiles (swizzled 16B chunks, 8B granular writes)
#pragma unroll
    for (int p = 0; p < 8; ++p) {
      int r = rg + 16 * p;
      float sc = wsc / (sqrtf(ssr[p]) + EPSF);
      float4 v = breg[p];
      v.x *= sc; v.y *= sc; v.z *= sc; v.w *= sc;
      ushort4 hv, lv;
      split2(v.x, hv.x, lv.x); split2(v.y, hv.y, lv.y);
      split2(v.z, hv.z, lv.z); split2(v.w, hv.w, lv.w);
      int widx = r * 64 + (((c16 >> 1) ^ (r & 7)) << 3) + ((c16 & 1) << 2);
      *(ushort4*)(Bh + widx) = hv;
      *(ushort4*)(Bl + widx) = lv;
    }
    // write A tiles
#pragma unroll
    for (int p = 0; p < 4; ++p) {
      int r = rg + 16 * p;
      int widx = r * 64 + (((c16 >> 1) ^ (r & 7)) << 3) + ((c16 & 1) << 2);
      *(ushort4*)(Ah + widx) = arh[p];
      *(ushort4*)(Al + widx) = arl[p];
    }
    __syncthreads();
    if (s < SA - 1) issueB(s + 1);   // flies during MFMA below
    // MFMA: K=64 as 2 steps of 16x16x32; 4 split passes
#pragma unroll
    for (int kk = 0; kk < 2; ++kk) {
      const int chp = (((kk * 4 + lq) ^ (lm & 7)) << 3);
      bf16x8 ah[4], al2[4], bh2[2], bl2[2];
#pragma unroll
      for (int mi = 0; mi < 4; ++mi) {
        int off = (mi * 16 + lm) * 64 + chp;
        ah[mi]  = *(const bf16x8*)(Ah + off);
        al2[mi] = *(const bf16x8*)(Al + off);
      }
#pragma unroll
      for (int ni = 0; ni < 2; ++ni) {
        int off = (wn0 + ni * 16 + lm) * 64 + chp;
        bh2[ni] = *(const bf16x8*)(Bh + off);
        bl2[ni] = *(const bf16x8*)(Bl + off);
      }
#pragma unroll
      for (int mi = 0; mi < 4; ++mi)
#pragma unroll
        for (int ni = 0; ni < 2; ++ni) {
          acc[mi][ni] = __builtin_amdgcn_mfma_f32_16x16x32_bf16(ah[mi],  bh2[ni], acc[mi][ni], 0, 0, 0);
          acc[mi][ni] = __builtin_amdgcn_mfma_f32_16x16x32_bf16(ah[mi],  bl2[ni], acc[mi][ni], 0, 0, 0);
          acc[mi][ni] = __builtin_amdgcn_mfma_f32_16x16x32_bf16(al2[mi], bh2[ni], acc[mi][ni], 0, 0, 0);
          acc[mi][ni] = __builtin_amdgcn_mfma_f32_16x16x32_bf16(al2[mi], bl2[ni], acc[mi][ni], 0, 0, 0);
        }
    }
    __syncthreads();
  }
  // epilogue: C/D layout col=lane&15 (n), row=(lane>>4)*4+reg (b)
  // store si + accumulate R-partials rs[mi][r] = sum over this lane's n's of g*exp(x)
  const float lam = lam_p[0], tau = tau_p[0];
  float rs[4][4];
#pragma unroll
  for (int mi = 0; mi < 4; ++mi)
#pragma unroll
    for (int r = 0; r < 4; ++r) rs[mi][r] = 0.f;
#pragma unroll
  for (int mi = 0; mi < 4; ++mi)
#pragma unroll
    for (int ni = 0; ni < 2; ++ni) {
      int n = n0 + wn0 + ni * 16 + lm;
      if (n < NKEYS) {
#pragma unroll
        for (int r = 0; r < 4; ++r) {
          int m = mi * 16 + lq * 4 + r;
          float x = acc[mi][ni][r];
          si[(size_t)m * NP + n] = x;
          float g = 1.f / (1.f + __expf(-lam * (x - tau)));
          rs[mi][r] = fmaf(g, __expf(x), rs[mi][r]);
        }
      }
    }
  // reduce each rs over the 16 lanes (lm) sharing that b; butterfly -> all lanes hold sum
#pragma unroll
  for (int mi = 0; mi < 4; ++mi)
#pragma unroll
    for (int r = 0; r < 4; ++r) {
      rs[mi][r] += __shfl_xor(rs[mi][r], 1);
      rs[mi][r] += __shfl_xor(rs[mi][r], 2);
      rs[mi][r] += __shfl_xor(rs[mi][r], 4);
      rs[mi][r] += __shfl_xor(rs[mi][r], 8);
    }
  // lane (lq,lm) writes the partial for b = (lm>>2)*16 + lq*4 + (lm&3)
  // static selection (rule: no runtime-indexed register arrays)
  float rout = rs[0][0];
#pragma unroll
  for (int mi = 0; mi < 4; ++mi)
#pragma unroll
    for (int r = 0; r < 4; ++r)
      if (lm == mi * 4 + r) rout = rs[mi][r];
  const int bsel = ((lm >> 2) << 4) + (lq << 2) + (lm & 3);
  Rp2[(size_t)bsel * NRPP + blockIdx.x * 4 + wave] = rout;
}

// ---------------- kernel 3a: per-(b,slice) top-32 (pure scan; R moved to k_sim) ----------------
// 512 blocks (b*8+slice) x 256 thr (4 waves); chunks c = sl + 8*wv + 32j.
__global__ __launch_bounds__(256) void k_topk_a(const float* __restrict__ si,
                                                float* __restrict__ candv,
                                                int* __restrict__ candi) {
  const int b = blockIdx.x >> 3, sl = blockIdx.x & 7;
  const int tid = threadIdx.x, wave = tid >> 6, lane = tid & 63;
  const float* row = si + (size_t)b * NP;

  float cv = -INFINITY; int ci = 0;
  float thr = -INFINITY;

  int c = sl + 8 * wave;
  float4 f0 = *(const float4*)(row + c * 256 + lane * 4);
  int cn = (c + 32 < 391) ? c + 32 : c;
  float4 f1 = *(const float4*)(row + cn * 256 + lane * 4);
  while (c < 391) {
    const int n0 = c * 256;
    float4 v4 = f0;
    f0 = f1;
    int cp = (c + 64 < 391) ? c + 64 : c;
    f1 = *(const float4*)(row + cp * 256 + lane * 4);
    c += 32;
#pragma unroll
    for (int e = 0; e < 4; ++e) {
      float x = (e == 0) ? v4.x : (e == 1) ? v4.y : (e == 2) ? v4.z : v4.w;
      int n = n0 + lane * 4 + e;
      bool valid = n < NKEYS;
      unsigned long long m = __ballot(valid && (x > thr));
      while (m) {
        int src = __ffsll((unsigned long long)m) - 1;
        m &= m - 1;
        float xv = __shfl(x, src);
        int xi = n0 + src * 4 + e;
        bool bigger = (cv > xv) || (cv == xv && ci < xi);
        unsigned long long bm = __ballot(bigger);
        int pos = __popcll(bm);
        float sv = __shfl_up(cv, 1);
        int sidx = __shfl_up(ci, 1);
        if (lane == pos)      { cv = xv; ci = xi; }
        else if (lane > pos)  { cv = sv; ci = sidx; }
        thr = __shfl(cv, 31);
      }
    }
  }

  __shared__ float lv[4][64];
  __shared__ int   li[4][64];
  lv[wave][lane] = cv; li[wave][lane] = ci;
  __syncthreads();

  if (wave == 0) {
    for (int w = 1; w < 4; ++w) {
      float nv = lv[w][lane]; int ni = li[w][lane];
      float rv = __shfl_xor(nv, 63); int ri = __shfl_xor(ni, 63);
      bool take = (rv > cv) || (rv == cv && ri < ci);
      if (take) { cv = rv; ci = ri; }
#pragma unroll
      for (int j = 32; j; j >>= 1) {
        float ov = __shfl_xor(cv, j); int oi = __shfl_xor(ci, j);
        bool lower = (lane & j) == 0;
        bool ob = (ov > cv) || (ov == cv && oi < ci);
        if (ob == lower) { cv = ov; ci = oi; }
      }
    }
    if (lane < KMAX) {
      candv[(b * 8 + sl) * KMAX + lane] = cv;
      candi[(b * 8 + sl) * KMAX + lane] = ci;
    }
  }
}

// ---------------- kernel 3b: merge 8 sorted top-32 lists per b + R reduce + epilogue ----------------
__global__ __launch_bounds__(64) void k_topk_b(const float* __restrict__ candv,
                                               const int* __restrict__ candi,
                                               const float* __restrict__ Rp2,
                                               const float* __restrict__ lam_p,
                                               const float* __restrict__ tau_p,
                                               const int* __restrict__ warm_p,
                                               float* __restrict__ out) {
  const int b = blockIdx.x, lane = threadIdx.x;
  const float lam = lam_p[0], tau = tau_p[0];
  const int warm = warm_p[0];

  // R[b] = sum of 3128 per-(block,wave) partials (b-major, coalesced)
  float R = 0.f;
  for (int i = lane; i < NRP; i += 64) R += Rp2[(size_t)b * NRPP + i];
#pragma unroll
  for (int o = 32; o; o >>= 1) R += __shfl_xor(R, o);

  float cv = (lane < KMAX) ? candv[b * 8 * KMAX + lane] : -INFINITY;
  int   ci = (lane < KMAX) ? candi[b * 8 * KMAX + lane] : 0x7FFFFFFF;
  for (int sl = 1; sl < 8; ++sl) {
    float nv = (lane < KMAX) ? candv[(b * 8 + sl) * KMAX + lane] : -INFINITY;
    int   ni = (lane < KMAX) ? candi[(b * 8 + sl) * KMAX + lane] : 0x7FFFFFFF;
    float rv = __shfl_xor(nv, 63); int ri = __shfl_xor(ni, 63);
    bool take = (rv > cv) || (rv == cv && ri < ci);
    if (take) { cv = rv; ci = ri; }
#pragma unroll
    for (int j = 32; j; j >>= 1) {
      float ov = __shfl_xor(cv, j); int oi = __shfl_xor(ci, j);
      bool lower = (lane & j) == 0;
      bool ob = (ov > cv) || (ov == cv && oi < ci);
      if (ob == lower) { cv = ov; ci = oi; }
    }
  }
  float t = 0.f;
  if (warm) {
    float mm = __shfl(cv, 0);
    if (lane < KMAX) t = __expf(cv - mm);
    float ssum = t;
#pragma unroll
    for (int o = 32; o; o >>= 1) ssum += __shfl_xor(ssum, o);
    if (lane < KMAX) {
      out[b * KMAX + lane] = t / ssum;
      out[BB * KMAX + b * KMAX + lane] = (float)ci;
    }
  } else {
    if (lane < KMAX) {
      float g = 1.f / (1.f + __expf(-lam * (cv - tau)));
      t = g * __expf(cv) / (R + EPSF);
    }
    float ssum = t;
#pragma unroll
    for (int o = 32; o; o >>= 1) ssum += __shfl_xor(ssum, o);
    if (lane < KMAX) {
      out[b * KMAX + lane] = t / (ssum + EPSF);
      out[BB * KMAX + b * KMAX + lane] = (float)ci;
    }
  }
}

extern "C" void kernel_launch(void* const* d_in, const int* in_sizes, int n_in,
                              void* d_out, int out_size, void* d_ws, size_t ws_size,
                              hipStream_t stream) {
  const float* z   = (const float*)d_in[0];
  const float* pk  = (const float*)d_in[1];
  const float* WQ  = (const float*)d_in[2];
  const float* aw  = (const float*)d_in[3];
  const float* tau = (const float*)d_in[4];
  const float* lam = (const float*)d_in[5];
  const int* warm  = (const int*)d_in[6];
  float* out = (float*)d_out;

  // workspace layout (float units):
  //   q     [0,     32768)              32768
  //   wbuf  [32768, 32776) pad-> 33344
  //   candv [33344, 49728)              16384 = 64b*8sl*32
  //   candi [49728, 66112)              16384
  //   qh    [66112, 82496)              32768 ushort = 16384 floats
  //   ql    [82496, 98880)              16384 floats
  //   si    [98880, 98880+64*NP)        6406144  -> end 6505024
  //   Rp2   [6505024, 6505024+64*NRPP)  200704   -> end 6705728 (~26.8 MB)
  float* w = (float*)d_ws;
  float* q     = w;
  float* wbuf  = w + 32768;
  float* candv = w + 33344;
  int*   candi = (int*)(w + 49728);
  unsigned short* qh = (unsigned short*)(w + 66112);
  unsigned short* ql = (unsigned short*)(w + 82496);
  float* si    = w + 98880;
  float* Rp2   = w + 6505024;

  k_queries<<<dim3(8192), 256, 0, stream>>>(z, WQ, q);
  k_norm<<<dim3(128), 256, 0, stream>>>(q, aw, qh, ql, wbuf);
  k_sim<<<dim3(NBLK), 256, 0, stream>>>(pk, qh, ql, wbuf, lam, tau, si, Rp2);
  k_topk_a<<<dim3(512), 256, 0, stream>>>(si, candv, candi);
  k_topk_b<<<dim3(BB), 64, 0, stream>>>(candv, candi, Rp2, lam, tau, warm, out);
}

// Round 7
// 371.428 us; speedup vs baseline: 1.0448x; 1.0448x over previous
//
#include <hip/hip_runtime.h>
#include <math.h>

#define SA    8
#define NKEYS 100000
#define NP    100096      // padded row stride for s_i (782*128)
#define DK    64
#define DA    2048
#define BB    64
#define KMAX  32
static constexpr float EPSF = 1e-8f;

typedef short  bf16x8 __attribute__((ext_vector_type(8)));
typedef float  f32x4  __attribute__((ext_vector_type(4)));

// RNE bf16 split: x ~= hi + lo, residual <= 2^-18 |x|
__device__ inline void split2(float x, unsigned short& h, unsigned short& l) {
  unsigned u = __float_as_uint(x);
  unsigned r = u + 0x7FFFu + ((u >> 16) & 1u);
  h = (unsigned short)(r >> 16);
  float hf = __uint_as_float(r & 0xFFFF0000u);
  float lo = x - hf;                    // exact
  unsigned ul = __float_as_uint(lo);
  unsigned rl = ul + 0x7FFFu + ((ul >> 16) & 1u);
  l = (unsigned short)(rl >> 16);
}

// ---------------- kernel 1: queries[b,s,k] = sum_a W_Q[s,k,a]*z[b,a] ----------------
// one wave per (b,s,k) dot of length 2048; fully coalesced.
// MEASURED CHAMPION. Do not retile (r0/r4: 4x4 and 2x2 retiles both <= 0);
// do not fuse topk (r0: -39); do not move R here (r6: -15).
__global__ __launch_bounds__(256) void k_queries(const float* __restrict__ z,
                                                 const float* __restrict__ WQ,
                                                 float* __restrict__ q) {
  const int t = blockIdx.x * 4 + (threadIdx.x >> 6);   // 0..32767 = b*512 + s*64 + k
  const int lane = threadIdx.x & 63;
  const int b = t >> 9, sk = t & 511;
  const float4* w4 = (const float4*)WQ + (size_t)sk * 512;
  const float4* z4 = (const float4*)z + (size_t)b * 512;
  float acc = 0.f;
#pragma unroll
  for (int i = 0; i < 8; ++i) {
    float4 a = w4[lane + 64 * i];
    float4 c = z4[lane + 64 * i];
    acc = fmaf(a.x, c.x, fmaf(a.y, c.y, fmaf(a.z, c.z, fmaf(a.w, c.w, acc))));
  }
#pragma unroll
  for (int o = 32; o; o >>= 1) acc += __shfl_xor(acc, o);
  if (lane == 0) q[(b * SA + (sk >> 6)) * DK + (sk & 63)] = acc;
}

// ---------------- kernel 1b: normalize q rows, split to bf16 hi/lo [s][b][k]; softmax(aw) ----------------
__global__ __launch_bounds__(256) void k_norm(const float* __restrict__ q,
                                              const float* __restrict__ aw,
                                              unsigned short* __restrict__ qh,
                                              unsigned short* __restrict__ ql,
                                              float* __restrict__ wbuf) {
  const int t = blockIdx.x * 4 + (threadIdx.x >> 6);   // 0..511 = b*8+s
  const int lane = threadIdx.x & 63;
  float x = q[t * DK + lane];
  float ss = x * x;
#pragma unroll
  for (int o = 32; o; o >>= 1) ss += __shfl_xor(ss, o);
  float xn = x / (sqrtf(ss) + EPSF);
  unsigned short h, l;
  split2(xn, h, l);
  const int b = t >> 3, s = t & 7;
  const int o = (s * BB + b) * DK + lane;
  qh[o] = h; ql[o] = l;
  if (blockIdx.x == 0 && threadIdx.x == 0) {
    float m = -INFINITY;
    for (int s2 = 0; s2 < SA; ++s2) m = fmaxf(m, aw[s2]);
    float e[SA], sum = 0.f;
    for (int s2 = 0; s2 < SA; ++s2) { e[s2] = __expf(aw[s2] - m); sum += e[s2]; }
    for (int s2 = 0; s2 < SA; ++s2) wbuf[s2] = e[s2] / sum;
  }
}

// ---------------- kernel 2: s_i via 4-pass split-bf16 MFMA ----------------
// 782 blocks x 256 thr (4 waves). Block tile 64b x 128n; wave = 64b x 32n.
// LDS 48 KB -> 3 blocks/CU. Register-prefetch next s-tile during MFMA.
// HBM-floor-bound: 204.8 MB pk read ~= 33 us at 6.3 TB/s achievable.
__global__ __launch_bounds__(256, 3) void k_sim(const float* __restrict__ pk,
                                                const unsigned short* __restrict__ qh,
                                                const unsigned short* __restrict__ ql,
                                                const float* __restrict__ wbuf,
                                                float* __restrict__ si) {
  __shared__ unsigned short Ah[64 * 64], Al[64 * 64];     // 8 KB each
  __shared__ unsigned short Bh[128 * 64], Bl[128 * 64];   // 16 KB each
  const int tid = threadIdx.x;
  const int wave = tid >> 6, lane = tid & 63;
  const int n0 = blockIdx.x * 128;
  const int c16 = tid & 15;          // float4 column within row
  const int rg  = tid >> 4;          // 0..15 row group
  const int lm = lane & 15, lq = lane >> 4;
  const int wn0 = wave * 32;

  f32x4 acc[4][2];
#pragma unroll
  for (int mi = 0; mi < 4; ++mi)
#pragma unroll
    for (int ni = 0; ni < 2; ++ni) acc[mi][ni] = (f32x4){0.f, 0.f, 0.f, 0.f};

  float4 breg[8];
  auto issueB = [&](int s) {
#pragma unroll
    for (int p = 0; p < 8; ++p) {
      int n = n0 + rg + 16 * p; if (n >= NKEYS) n = NKEYS - 1;
      breg[p] = *(const float4*)(pk + ((size_t)s * NKEYS + n) * DK + c16 * 4);
    }
  };
  issueB(0);

  for (int s = 0; s < SA; ++s) {
    // A staging regs (qh/ql are tiny & L2-hot)
    ushort4 arh[4], arl[4];
#pragma unroll
    for (int p = 0; p < 4; ++p) {
      int r = rg + 16 * p;
      int o = (s * BB + r) * DK + c16 * 4;
      arh[p] = *(const ushort4*)(qh + o);
      arl[p] = *(const ushort4*)(ql + o);
    }
    const float wsc = wbuf[s];
    // per-row ||k||^2: partial dot + reduce over the 16 lanes sharing the row
    float ssr[8];
#pragma unroll
    for (int p = 0; p < 8; ++p) {
      float4 v = breg[p];
      float d = v.x * v.x + v.y * v.y + v.z * v.z + v.w * v.w;
      d += __shfl_xor(d, 1); d += __shfl_xor(d, 2);
      d += __shfl_xor(d, 4); d += __shfl_xor(d, 8);
      ssr[p] = d;
    }
    // scale, split, write B tiles (swizzled 16B chunks, 8B granular writes)
#pragma unroll
    for (int p = 0; p < 8; ++p) {
      int r = rg + 16 * p;
      float sc = wsc / (sqrtf(ssr[p]) + EPSF);
      float4 v = breg[p];
      v.x *= sc; v.y *= sc; v.z *= sc; v.w *= sc;
      ushort4 hv, lv;
      split2(v.x, hv.x, lv.x); split2(v.y, hv.y, lv.y);
      split2(v.z, hv.z, lv.z); split2(v.w, hv.w, lv.w);
      int widx = r * 64 + (((c16 >> 1) ^ (r & 7)) << 3) + ((c16 & 1) << 2);
      *(ushort4*)(Bh + widx) = hv;
      *(ushort4*)(Bl + widx) = lv;
    }
    // write A tiles
#pragma unroll
    for (int p = 0; p < 4; ++p) {
      int r = rg + 16 * p;
      int widx = r * 64 + (((c16 >> 1) ^ (r & 7)) << 3) + ((c16 & 1) << 2);
      *(ushort4*)(Ah + widx) = arh[p];
      *(ushort4*)(Al + widx) = arl[p];
    }
    __syncthreads();
    if (s < SA - 1) issueB(s + 1);   // flies during MFMA below
    // MFMA: K=64 as 2 steps of 16x16x32; 4 split passes
#pragma unroll
    for (int kk = 0; kk < 2; ++kk) {
      const int chp = (((kk * 4 + lq) ^ (lm & 7)) << 3);
      bf16x8 ah[4], al2[4], bh2[2], bl2[2];
#pragma unroll
      for (int mi = 0; mi < 4; ++mi) {
        int off = (mi * 16 + lm) * 64 + chp;
        ah[mi]  = *(const bf16x8*)(Ah + off);
        al2[mi] = *(const bf16x8*)(Al + off);
      }
#pragma unroll
      for (int ni = 0; ni < 2; ++ni) {
        int off = (wn0 + ni * 16 + lm) * 64 + chp;
        bh2[ni] = *(const bf16x8*)(Bh + off);
        bl2[ni] = *(const bf16x8*)(Bl + off);
      }
#pragma unroll
      for (int mi = 0; mi < 4; ++mi)
#pragma unroll
        for (int ni = 0; ni < 2; ++ni) {
          acc[mi][ni] = __builtin_amdgcn_mfma_f32_16x16x32_bf16(ah[mi],  bh2[ni], acc[mi][ni], 0, 0, 0);
          acc[mi][ni] = __builtin_amdgcn_mfma_f32_16x16x32_bf16(ah[mi],  bl2[ni], acc[mi][ni], 0, 0, 0);
          acc[mi][ni] = __builtin_amdgcn_mfma_f32_16x16x32_bf16(al2[mi], bh2[ni], acc[mi][ni], 0, 0, 0);
          acc[mi][ni] = __builtin_amdgcn_mfma_f32_16x16x32_bf16(al2[mi], bl2[ni], acc[mi][ni], 0, 0, 0);
        }
    }
    __syncthreads();
  }
  // epilogue: C/D layout col=lane&15 (n), row=(lane>>4)*4+reg (b)
#pragma unroll
  for (int mi = 0; mi < 4; ++mi)
#pragma unroll
    for (int ni = 0; ni < 2; ++ni) {
      int n = n0 + wn0 + ni * 16 + lm;
      if (n < NKEYS) {
#pragma unroll
        for (int r = 0; r < 4; ++r) {
          int m = mi * 16 + lq * 4 + r;
          si[(size_t)m * NP + n] = acc[mi][ni][r];
        }
      }
    }
}

// ---------------- kernel 3a: per-(b,slice) top-32 + partial R ----------------
// 512 blocks (b*8+slice) x 256 thr (4 waves); chunks c = sl + 8*wv + 32j.
__global__ __launch_bounds__(256) void k_topk_a(const float* __restrict__ si,
                                                const float* __restrict__ lam_p,
                                                const float* __restrict__ tau_p,
                                                float* __restrict__ candv,
                                                int* __restrict__ candi,
                                                float* __restrict__ Rp) {
  const int b = blockIdx.x >> 3, sl = blockIdx.x & 7;
  const int tid = threadIdx.x, wave = tid >> 6, lane = tid & 63;
  const float lam = lam_p[0], tau = tau_p[0];
  const float* row = si + (size_t)b * NP;

  float cv = -INFINITY; int ci = 0;
  float r = 0.f;
  float thr = -INFINITY;

  int c = sl + 8 * wave;
  float4 f0 = *(const float4*)(row + c * 256 + lane * 4);
  int cn = (c + 32 < 391) ? c + 32 : c;
  float4 f1 = *(const float4*)(row + cn * 256 + lane * 4);
  while (c < 391) {
    const int n0 = c * 256;
    float4 v4 = f0;
    f0 = f1;
    int cp = (c + 64 < 391) ? c + 64 : c;
    f1 = *(const float4*)(row + cp * 256 + lane * 4);
    c += 32;
#pragma unroll
    for (int e = 0; e < 4; ++e) {
      float x = (e == 0) ? v4.x : (e == 1) ? v4.y : (e == 2) ? v4.z : v4.w;
      int n = n0 + lane * 4 + e;
      bool valid = n < NKEYS;
      if (valid) {
        float g = 1.f / (1.f + __expf(-lam * (x - tau)));
        r += g * __expf(x);
      }
      unsigned long long m = __ballot(valid && (x > thr));
      while (m) {
        int src = __ffsll((unsigned long long)m) - 1;
        m &= m - 1;
        float xv = __shfl(x, src);
        int xi = n0 + src * 4 + e;
        bool bigger = (cv > xv) || (cv == xv && ci < xi);
        unsigned long long bm = __ballot(bigger);
        int pos = __popcll(bm);
        float sv = __shfl_up(cv, 1);
        int sidx = __shfl_up(ci, 1);
        if (lane == pos)      { cv = xv; ci = xi; }
        else if (lane > pos)  { cv = sv; ci = sidx; }
        thr = __shfl(cv, 31);
      }
    }
  }
#pragma unroll
  for (int o = 32; o; o >>= 1) r += __shfl_xor(r, o);

  __shared__ float lv[4][64];
  __shared__ int   li[4][64];
  __shared__ float lr[4];
  lv[wave][lane] = cv; li[wave][lane] = ci;
  if (lane == 0) lr[wave] = r;
  __syncthreads();

  if (wave == 0) {
    float R = lr[0] + lr[1] + lr[2] + lr[3];
    for (int w = 1; w < 4; ++w) {
      float nv = lv[w][lane]; int ni = li[w][lane];
      float rv = __shfl_xor(nv, 63); int ri = __shfl_xor(ni, 63);
      bool take = (rv > cv) || (rv == cv && ri < ci);
      if (take) { cv = rv; ci = ri; }
#pragma unroll
      for (int j = 32; j; j >>= 1) {
        float ov = __shfl_xor(cv, j); int oi = __shfl_xor(ci, j);
        bool lower = (lane & j) == 0;
        bool ob = (ov > cv) || (ov == cv && oi < ci);
        if (ob == lower) { cv = ov; ci = oi; }
      }
    }
    if (lane < KMAX) {
      candv[(b * 8 + sl) * KMAX + lane] = cv;
      candi[(b * 8 + sl) * KMAX + lane] = ci;
    }
    if (lane == 0) Rp[b * 8 + sl] = R;
  }
}

// ---------------- kernel 3b: merge 8 sorted top-32 lists per b + epilogue ----------------
__global__ __launch_bounds__(64) void k_topk_b(const float* __restrict__ candv,
                                               const int* __restrict__ candi,
                                               const float* __restrict__ Rp,
                                               const float* __restrict__ lam_p,
                                               const float* __restrict__ tau_p,
                                               const int* __restrict__ warm_p,
                                               float* __restrict__ out) {
  const int b = blockIdx.x, lane = threadIdx.x;
  const float lam = lam_p[0], tau = tau_p[0];
  const int warm = warm_p[0];

  float R = 0.f;
#pragma unroll
  for (int sl = 0; sl < 8; ++sl) R += Rp[b * 8 + sl];

  float cv = (lane < KMAX) ? candv[b * 8 * KMAX + lane] : -INFINITY;
  int   ci = (lane < KMAX) ? candi[b * 8 * KMAX + lane] : 0x7FFFFFFF;
  for (int sl = 1; sl < 8; ++sl) {
    float nv = (lane < KMAX) ? candv[(b * 8 + sl) * KMAX + lane] : -INFINITY;
    int   ni = (lane < KMAX) ? candi[(b * 8 + sl) * KMAX + lane] : 0x7FFFFFFF;
    float rv = __shfl_xor(nv, 63); int ri = __shfl_xor(ni, 63);
    bool take = (rv > cv) || (rv == cv && ri < ci);
    if (take) { cv = rv; ci = ri; }
#pragma unroll
    for (int j = 32; j; j >>= 1) {
      float ov = __shfl_xor(cv, j); int oi = __shfl_xor(ci, j);
      bool lower = (lane & j) == 0;
      bool ob = (ov > cv) || (ov == cv && oi < ci);
      if (ob == lower) { cv = ov; ci = oi; }
    }
  }
  float t = 0.f;
  if (warm) {
    float mm = __shfl(cv, 0);
    if (lane < KMAX) t = __expf(cv - mm);
    float ssum = t;
#pragma unroll
    for (int o = 32; o; o >>= 1) ssum += __shfl_xor(ssum, o);
    if (lane < KMAX) {
      out[b * KMAX + lane] = t / ssum;
      out[BB * KMAX + b * KMAX + lane] = (float)ci;
    }
  } else {
    if (lane < KMAX) {
      float g = 1.f / (1.f + __expf(-lam * (cv - tau)));
      t = g * __expf(cv) / (R + EPSF);
    }
    float ssum = t;
#pragma unroll
    for (int o = 32; o; o >>= 1) ssum += __shfl_xor(ssum, o);
    if (lane < KMAX) {
      out[b * KMAX + lane] = t / (ssum + EPSF);
      out[BB * KMAX + b * KMAX + lane] = (float)ci;
    }
  }
}

extern "C" void kernel_launch(void* const* d_in, const int* in_sizes, int n_in,
                              void* d_out, int out_size, void* d_ws, size_t ws_size,
                              hipStream_t stream) {
  const float* z   = (const float*)d_in[0];
  const float* pk  = (const float*)d_in[1];
  const float* WQ  = (const float*)d_in[2];
  const float* aw  = (const float*)d_in[3];
  const float* tau = (const float*)d_in[4];
  const float* lam = (const float*)d_in[5];
  const int* warm  = (const int*)d_in[6];
  float* out = (float*)d_out;

  // workspace layout (float units); sizes verified:
  //   q     [0,     32768)              32768
  //   wbuf  [32768, 32776) pad-> 32832
  //   Rp    [32832, 33344)                512
  //   candv [33344, 49728)              16384 = 64b*8sl*32
  //   candi [49728, 66112)              16384
  //   qh    [66112, 82496)              32768 ushort = 16384 floats
  //   ql    [82496, 98880)              16384 floats
  //   si    [98880, 98880+64*NP)        6406144
  float* w = (float*)d_ws;
  float* q     = w;
  float* wbuf  = w + 32768;
  float* Rp    = w + 32832;
  float* candv = w + 33344;
  int*   candi = (int*)(w + 49728);
  unsigned short* qh = (unsigned short*)(w + 66112);
  unsigned short* ql = (unsigned short*)(w + 82496);
  float* si    = w + 98880;

  k_queries<<<dim3(8192), 256, 0, stream>>>(z, WQ, q);
  k_norm<<<dim3(128), 256, 0, stream>>>(q, aw, qh, ql, wbuf);
  k_sim<<<dim3((NKEYS + 127) / 128), 256, 0, stream>>>(pk, qh, ql, wbuf, si);
  k_topk_a<<<dim3(512), 256, 0, stream>>>(si, lam, tau, candv, candi, Rp);
  k_topk_b<<<dim3(BB), 64, 0, stream>>>(candv, candi, Rp, lam, tau, warm, out);
}